// Round 9
// baseline (553.348 us; speedup 1.0000x reference)
//
#include <hip/hip_runtime.h>
#include <hip/hip_bf16.h>
#include <math.h>
#include <stdint.h>

#define N_NODES 40000
#define N_EDGES 640000

typedef short short8 __attribute__((ext_vector_type(8)));
typedef float f32x4 __attribute__((ext_vector_type(4)));

__device__ __forceinline__ float silu(float x) {
    return __fdividef(x, 1.0f + __expf(-x));
}

__device__ __forceinline__ unsigned short f2bf(float f) {
    unsigned u = __float_as_uint(f);
    u += 0x7FFF + ((u >> 16) & 1);
    return (unsigned short)(u >> 16);
}
__device__ __forceinline__ float bf2f(unsigned short h) {
    return __uint_as_float(((unsigned)h) << 16);
}
__device__ __forceinline__ unsigned pk2bf(float a, float b) {
    __hip_bfloat162 h = __float22bfloat162_rn(make_float2(a, b));
    unsigned u;
    __builtin_memcpy(&u, &h, 4);
    return u;
}

// ---------------------------------------------------------------------------
// k_scanA: 40 blocks x 1024 threads; block b does an EXCLUSIVE scan of
// deg[b*1000 .. b*1000+999] -> rsl, and writes its block total to btot[b].
// ---------------------------------------------------------------------------
__global__ __launch_bounds__(1024) void k_scanA(const int* __restrict__ deg,
                                                int* __restrict__ rsl,
                                                int* __restrict__ btot) {
    __shared__ int wsum[16];
    const int t = threadIdx.x;
    const int lane = t & 63, wid = t >> 6;
    const int base = blockIdx.x * 1000;
    const int x0 = (t < 1000) ? deg[base + t] : 0;
    int x = x0;
#pragma unroll
    for (int s = 1; s < 64; s <<= 1) {
        const int u = __shfl_up(x, s, 64);
        if (lane >= s) x += u;
    }
    if (lane == 63) wsum[wid] = x;
    __syncthreads();
    if (wid == 0) {
        int ws = (lane < 16) ? wsum[lane] : 0;
#pragma unroll
        for (int s = 1; s < 16; s <<= 1) {
            const int u = __shfl_up(ws, s, 64);
            if (lane >= s) ws += u;
        }
        if (lane < 16) wsum[lane] = ws;
    }
    __syncthreads();
    const int wbase = (wid > 0) ? wsum[wid - 1] : 0;
    if (t < 1000) rsl[base + t] = wbase + x - x0;   // exclusive within block
    if (t == 0) btot[blockIdx.x] = wsum[15];
}

// ---------------------------------------------------------------------------
// k_fill: scanB FUSED — wave 0 of each block redundantly scans the 40 block
// totals (trivial) into LDS, then global CSR pos = sbo[d/1000]+rsl[d]+cursor.
// ---------------------------------------------------------------------------
__global__ __launch_bounds__(256) void k_fill(const int* __restrict__ dst,
                                              const int* __restrict__ rsl,
                                              const int* __restrict__ btot,
                                              int* __restrict__ cursor,
                                              int* __restrict__ elist) {
    __shared__ int sbo[40];
    const int t = threadIdx.x;
    if (t < 64) {
        const int x0 = (t < 40) ? btot[t] : 0;
        int x = x0;
#pragma unroll
        for (int s = 1; s < 64; s <<= 1) {
            const int u = __shfl_up(x, s, 64);
            if (t >= s) x += u;
        }
        if (t < 40) sbo[t] = x - x0;
    }
    __syncthreads();
    const int e = blockIdx.x * 256 + t;
    if (e < N_EDGES) {
        const int d = dst[e];
        const int p = atomicAdd(&cursor[d], 1);
        elist[sbo[d / 1000] + rsl[d] + p] = e;
    }
}

// ---------------------------------------------------------------------------
// k_pack2: bf16-transposed weight packs + folded memsets (deg/cursor/xs/hn).
// ---------------------------------------------------------------------------
__global__ __launch_bounds__(128) void k_pack2(
    const float* __restrict__ We1, const float* __restrict__ We2,
    const float* __restrict__ Wc1, const float* __restrict__ Wn1,
    const float* __restrict__ Wn2,
    unsigned short* __restrict__ Wt_e1, unsigned short* __restrict__ Wt_e2,
    unsigned short* __restrict__ Wt_c1, unsigned short* __restrict__ Wt_n1,
    unsigned short* __restrict__ Wt_n2,
    int* __restrict__ deg, int* __restrict__ cursor, float* __restrict__ xs,
    float* __restrict__ hn) {
    const int b = blockIdx.x;   // 0..255
    const int t = threadIdx.x;  // 0..127
    Wt_e1[b * 128 + t] = f2bf(We1[(size_t)((b >> 7) * 128 + t) * 128 + (b & 127)]);
    if (b < 128) {
        Wt_e2[b * 128 + t] = f2bf(We2[(size_t)t * 128 + b]);
        Wt_c1[b * 128 + t] = f2bf(Wc1[(size_t)t * 128 + b]);
        Wt_n2[b * 128 + t] = f2bf(Wn2[(size_t)t * 128 + b]);
        Wt_n1[b * 256 + t] = f2bf(Wn1[(size_t)t * 128 + b]);
        Wt_n1[b * 256 + 128 + t] = f2bf(Wn1[(size_t)(128 + t) * 128 + b]);
    }
    const int gid = b * 128 + t;                   // 0..32767
    for (int i = gid; i < N_NODES; i += 32768) { deg[i] = 0; cursor[i] = 0; }
    for (int i = gid; i < N_NODES * 4; i += 32768) xs[i] = 0.0f;
    float4* hz = (float4*)hn;
    const float4 z4 = {0.f, 0.f, 0.f, 0.f};
    for (int i = gid; i < N_NODES * 32; i += 32768) hz[i] = z4;
}

// ---------------------------------------------------------------------------
// k_cntpre: dst-degree histogram fused with Pc = nf @ [We1a|We1b] (bf16).
// be1 is BAKED into the dst half (cols 128..255) so k_edge10 skips the add.
// ---------------------------------------------------------------------------
__global__ __launch_bounds__(256) void k_cntpre(
    const float* __restrict__ nf, const unsigned short* __restrict__ Wt_e1,
    const float* __restrict__ be1,
    unsigned short* __restrict__ Pc,
    const int* __restrict__ dst, int* __restrict__ deg) {
    __shared__ __align__(16) unsigned short sNF[32][136];
    const int t = threadIdx.x;
    const int node0 = blockIdx.x * 32;
    {
        const int e0 = (blockIdx.x * 256 + t) * 2;
        const int d0 = dst[e0], d1 = dst[e0 + 1];
        atomicAdd(&deg[d0], 1);
        atomicAdd(&deg[d1], 1);
    }
    {
        const int m = t >> 3, kc = (t & 7) * 16;
        const float* sp = &nf[(size_t)(node0 + m) * 128 + kc];
        const float4 v0 = *(const float4*)(sp + 0);
        const float4 v1 = *(const float4*)(sp + 4);
        const float4 v2 = *(const float4*)(sp + 8);
        const float4 v3 = *(const float4*)(sp + 12);
        int4 o0, o1;
        o0.x = pk2bf(v0.x, v0.y); o0.y = pk2bf(v0.z, v0.w);
        o0.z = pk2bf(v1.x, v1.y); o0.w = pk2bf(v1.z, v1.w);
        o1.x = pk2bf(v2.x, v2.y); o1.y = pk2bf(v2.z, v2.w);
        o1.z = pk2bf(v3.x, v3.y); o1.w = pk2bf(v3.z, v3.w);
        *(int4*)&sNF[m][kc] = o0;
        *(int4*)&sNF[m][kc + 8] = o1;
    }
    __syncthreads();

    const int w = t >> 6, l = t & 63, c = l & 15, quad = l >> 4;
    const int n0 = w * 64;

    f32x4 acc[2][4];
#pragma unroll
    for (int mt = 0; mt < 2; mt++)
#pragma unroll
        for (int tl = 0; tl < 4; tl++) acc[mt][tl] = (f32x4){0.f, 0.f, 0.f, 0.f};

#pragma unroll
    for (int k0 = 0; k0 < 128; k0 += 32) {
        const short8 a0 = *(const short8*)&sNF[c][k0 + quad * 8];
        const short8 a1 = *(const short8*)&sNF[16 + c][k0 + quad * 8];
#pragma unroll
        for (int tl = 0; tl < 4; tl++) {
            const short8 b = *(const short8*)(Wt_e1 +
                ((size_t)(n0 + tl * 16 + c) << 7) + k0 + quad * 8);
            acc[0][tl] = __builtin_amdgcn_mfma_f32_16x16x32_bf16(a0, b, acc[0][tl], 0, 0, 0);
            acc[1][tl] = __builtin_amdgcn_mfma_f32_16x16x32_bf16(a1, b, acc[1][tl], 0, 0, 0);
        }
    }
#pragma unroll
    for (int mt = 0; mt < 2; mt++)
#pragma unroll
        for (int tl = 0; tl < 4; tl++) {
            const int col = n0 + tl * 16 + c;
            const float bias = (col >= 128) ? be1[col - 128] : 0.0f;
            const unsigned p01 = pk2bf(acc[mt][tl][0] + bias, acc[mt][tl][1] + bias);
            const unsigned p23 = pk2bf(acc[mt][tl][2] + bias, acc[mt][tl][3] + bias);
            const int row = node0 + mt * 16 + quad * 4;
            Pc[(size_t)(row + 0) * 256 + col] = (unsigned short)p01;
            Pc[(size_t)(row + 1) * 256 + col] = (unsigned short)(p01 >> 16);
            Pc[(size_t)(row + 2) * 256 + col] = (unsigned short)p23;
            Pc[(size_t)(row + 3) * 256 + col] = (unsigned short)(p23 >> 16);
        }
}

// ---------------------------------------------------------------------------
// k_edge10: ONE-barrier edge pipeline. 64 edges / 256 threads / 4 waves;
// each wave owns 16 edges x full N=128 (M=16 per wave). Lane (c,quad)
// computes t1 for edge eb+c, cols k0*32+quad*8..+7 — exactly the MFMA
// A-fragment — directly in registers (no t1 LDS roundtrip, no duplication,
// same 32 silu/lane as edge9). Per-wave meta staging kills B0; sT holds
// only t2 (exclusive 16-row stripe per wave) so only ONE __syncthreads
// (t2 visible to cross-wave h-scatter). GEMM2 N=128/wave gives FULL coefs
// -> x-scatter run-head atomics once (was twice). sw read from global
// (L1-hot). Cost: B-frags loaded over full N per wave (2x weight traffic,
// L2-resident 64KB). VGPR ~80-100 expected (no min-waves hint).
// ---------------------------------------------------------------------------
__global__ __launch_bounds__(256) void k_edge10(
    const unsigned short* __restrict__ Pc, const float* __restrict__ coord,
    const int* __restrict__ src, const int* __restrict__ dst,
    const int* __restrict__ elist,
    const float* __restrict__ We1,
    const unsigned short* __restrict__ Wt_e2, const float* __restrict__ be2,
    const unsigned short* __restrict__ Wt_c1, const float* __restrict__ bc1,
    const float* __restrict__ Wc2,
    float* __restrict__ h_neigh, float* __restrict__ xs) {
    __shared__ __align__(16) unsigned short sT[64][136];   // t2 only: 17408 B
    __shared__ float scoef[4][16];
    __shared__ float sdist[64];
    __shared__ float sxd[64][3];
    __shared__ int ssrc[64];
    __shared__ int sdst[64];

    const int t = threadIdx.x;
    const int w = t >> 6, l = t & 63;
    const int c = l & 15, quad = l >> 4;
    const int bid = (int)blockIdx.x;
    const int swz = (bid & 7) * 1250 + (bid >> 3);   // bijective XCD chunking
    const int e0 = swz * 64;
    const int eb = w * 16;              // this wave's edge base (block-local)

    // ---- per-wave meta staging (lanes 0..15): wave-internal only ----
    if (l < 16) {
        const int eid = elist[e0 + eb + l];
        const int s = src[eid], d = dst[eid];
        ssrc[eb + l] = s; sdst[eb + l] = d;
        const float dx = coord[3 * s + 0] - coord[3 * d + 0];
        const float dy = coord[3 * s + 1] - coord[3 * d + 1];
        const float dz = coord[3 * s + 2] - coord[3 * d + 2];
        const float dist = sqrtf(dx * dx + dy * dy + dz * dz);
        sdist[eb + l] = dist;
        const float inv = __fdividef(1.0f, dist + 1e-7f);
        sxd[eb + l][0] = dx * inv; sxd[eb + l][1] = dy * inv; sxd[eb + l][2] = dz * inv;
    }
    asm volatile("s_waitcnt lgkmcnt(0)" ::: "memory");   // wave-internal fence

    // ---- t1 straight into A-fragments (gather + 32 silu per lane) ----
    short8 aQ[4];
    {
        const int er = eb + c;
        const int s = ssrc[er], d = sdst[er];
        const float dist = sdist[er];
        const unsigned short* p1 = Pc + (size_t)s * 256 + quad * 8;
        const unsigned short* p2 = Pc + (size_t)d * 256 + 128 + quad * 8;
        const float* wd = We1 + 256 * 128 + quad * 8;   // dist row, L1-hot
#pragma unroll
        for (int k0 = 0; k0 < 4; k0++) {
            const short8 a = *(const short8*)(p1 + k0 * 32);
            const short8 b = *(const short8*)(p2 + k0 * 32);
            const float4 w0 = *(const float4*)(wd + k0 * 32);
            const float4 w1 = *(const float4*)(wd + k0 * 32 + 4);
            float v[8];
            v[0] = silu(bf2f((unsigned short)a[0]) + bf2f((unsigned short)b[0]) + dist * w0.x);
            v[1] = silu(bf2f((unsigned short)a[1]) + bf2f((unsigned short)b[1]) + dist * w0.y);
            v[2] = silu(bf2f((unsigned short)a[2]) + bf2f((unsigned short)b[2]) + dist * w0.z);
            v[3] = silu(bf2f((unsigned short)a[3]) + bf2f((unsigned short)b[3]) + dist * w0.w);
            v[4] = silu(bf2f((unsigned short)a[4]) + bf2f((unsigned short)b[4]) + dist * w1.x);
            v[5] = silu(bf2f((unsigned short)a[5]) + bf2f((unsigned short)b[5]) + dist * w1.y);
            v[6] = silu(bf2f((unsigned short)a[6]) + bf2f((unsigned short)b[6]) + dist * w1.z);
            v[7] = silu(bf2f((unsigned short)a[7]) + bf2f((unsigned short)b[7]) + dist * w1.w);
            int4 o;
            o.x = pk2bf(v[0], v[1]); o.y = pk2bf(v[2], v[3]);
            o.z = pk2bf(v[4], v[5]); o.w = pk2bf(v[6], v[7]);
            __builtin_memcpy(&aQ[k0], &o, 16);
        }
    }

    // ---- GEMM1: t2_acc = t1 @ We2 (M=16/wave, N=128) — no barrier ----
    f32x4 acc1[8];
#pragma unroll
    for (int tl = 0; tl < 8; tl++) acc1[tl] = (f32x4){0.f, 0.f, 0.f, 0.f};
#pragma unroll
    for (int k0 = 0; k0 < 4; k0++) {
#pragma unroll
        for (int tl = 0; tl < 8; tl++) {
            const short8 b = *(const short8*)(Wt_e2 +
                ((size_t)(tl * 16 + c) << 7) + k0 * 32 + quad * 8);
            acc1[tl] = __builtin_amdgcn_mfma_f32_16x16x32_bf16(aQ[k0], b, acc1[tl], 0, 0, 0);
        }
    }

    // ---- t2 = silu(acc + be2) -> this wave's exclusive 16-row stripe ----
#pragma unroll
    for (int tl = 0; tl < 8; tl++) {
        const int col = tl * 16 + c;
        const float bb = be2[col];
        const unsigned p01 = pk2bf(silu(acc1[tl][0] + bb), silu(acc1[tl][1] + bb));
        const unsigned p23 = pk2bf(silu(acc1[tl][2] + bb), silu(acc1[tl][3] + bb));
        const int row = eb + quad * 4;
        sT[row + 0][col] = (unsigned short)p01;
        sT[row + 1][col] = (unsigned short)(p01 >> 16);
        sT[row + 2][col] = (unsigned short)p23;
        sT[row + 3][col] = (unsigned short)(p23 >> 16);
    }
    __syncthreads();   // THE only block-wide barrier

    // ---- h-scatter: two independent 16-row chains (2x ILP); atomics
    //      drain under GEMM2's MFMAs ----
    {
        const int j = t & 127;
        const int q = t >> 7;
        const int ebq = q * 32;
        float aA = bf2f(sT[ebq][j]);      int pA = sdst[ebq];
        float aB = bf2f(sT[ebq + 16][j]); int pB = sdst[ebq + 16];
#pragma unroll
        for (int i = 1; i < 16; i++) {
            const int dA = sdst[ebq + i];
            const int dB = sdst[ebq + 16 + i];
            const float vA = bf2f(sT[ebq + i][j]);
            const float vB = bf2f(sT[ebq + 16 + i][j]);
            if (dA != pA) { atomicAdd(&h_neigh[(size_t)pA * 128 + j], aA); aA = 0.f; pA = dA; }
            aA += vA;
            if (dB != pB) { atomicAdd(&h_neigh[(size_t)pB * 128 + j], aB); aB = 0.f; pB = dB; }
            aB += vB;
        }
        atomicAdd(&h_neigh[(size_t)pA * 128 + j], aA);
        atomicAdd(&h_neigh[(size_t)pB * 128 + j], aB);
    }

    // ---- GEMM2: coef = silu(t2 @ Wc1 + bc1) . Wc2 (M=16/wave, N=128) ----
    {
        short8 a2[4];
#pragma unroll
        for (int k0 = 0; k0 < 4; k0++)
            a2[k0] = *(const short8*)&sT[eb + c][k0 * 32 + quad * 8];

        f32x4 acc2[8];
#pragma unroll
        for (int tl = 0; tl < 8; tl++) acc2[tl] = (f32x4){0.f, 0.f, 0.f, 0.f};
#pragma unroll
        for (int k0 = 0; k0 < 4; k0++) {
#pragma unroll
            for (int tl = 0; tl < 8; tl++) {
                const short8 b = *(const short8*)(Wt_c1 +
                    ((size_t)(tl * 16 + c) << 7) + k0 * 32 + quad * 8);
                acc2[tl] = __builtin_amdgcn_mfma_f32_16x16x32_bf16(a2[k0], b, acc2[tl], 0, 0, 0);
            }
        }
        float part[4] = {0.f, 0.f, 0.f, 0.f};
#pragma unroll
        for (int tl = 0; tl < 8; tl++) {
            const int col = tl * 16 + c;
            const float bc = bc1[col];
            const float wc = Wc2[col];
#pragma unroll
            for (int r = 0; r < 4; r++)
                part[r] += silu(acc2[tl][r] + bc) * wc;
        }
        // reduce over the 16 c-lanes (full N=128 -> FULL coef)
#pragma unroll
        for (int off = 1; off < 16; off <<= 1) {
#pragma unroll
            for (int r = 0; r < 4; r++)
                part[r] += __shfl_xor(part[r], off, 64);
        }
        if (c == 0) {
#pragma unroll
            for (int r = 0; r < 4; r++)
                scoef[w][quad * 4 + r] = part[r];
        }
    }
    asm volatile("s_waitcnt lgkmcnt(0)" ::: "memory");   // wave-internal fence

    // ---- x-scatter: 16-lane segmented suffix-sum, FULL coefs, run heads
    //      emit one atomic per run ----
    if (l < 16) {
        const int e = eb + l;
        const int dd = sdst[e];
        const float cf = scoef[w][l];
        float v0 = cf * sxd[e][0];
        float v1 = cf * sxd[e][1];
        float v2 = cf * sxd[e][2];
#pragma unroll
        for (int s = 1; s < 16; s <<= 1) {
            const float u0 = __shfl_down(v0, s, 64);
            const float u1 = __shfl_down(v1, s, 64);
            const float u2 = __shfl_down(v2, s, 64);
            const int ud = __shfl_down(dd, s, 64);
            if (l + s < 16 && ud == dd) { v0 += u0; v1 += u1; v2 += u2; }
        }
        if (e == 0 || sdst[e - 1] != dd) {
            atomicAdd(&xs[(size_t)dd * 4 + 0], v0);
            atomicAdd(&xs[(size_t)dd * 4 + 1], v1);
            atomicAdd(&xs[(size_t)dd * 4 + 2], v2);
        }
    }
}

// ---------------------------------------------------------------------------
// k_node (MFMA): h = silu([nf|hn] @ Wn1 + bn1) @ Wn2 + bn2 ; x = coord+xs/cnt
// cnt comes straight from deg.
// ---------------------------------------------------------------------------
__global__ __launch_bounds__(256) void k_node(
    const float* __restrict__ nf, const float* __restrict__ coord,
    const float* __restrict__ hn, const float* __restrict__ xs,
    const int* __restrict__ deg,
    const unsigned short* __restrict__ Wt_n1, const float* __restrict__ bn1,
    const unsigned short* __restrict__ Wt_n2, const float* __restrict__ bn2,
    float* __restrict__ out_h, float* __restrict__ out_x) {
    __shared__ __align__(16) unsigned short sAB[32][264];
    __shared__ __align__(16) unsigned short sH[32][136];
    const int t = threadIdx.x;
    const int node0 = blockIdx.x * 32;
    {
        const int m = t >> 3, kc = (t & 7) * 32;
        const float* base = (kc < 128) ? &nf[(size_t)(node0 + m) * 128 + kc]
                                       : &hn[(size_t)(node0 + m) * 128 + (kc - 128)];
#pragma unroll
        for (int kk = 0; kk < 32; kk += 8) {
            const float4 v0 = *(const float4*)(base + kk);
            const float4 v1 = *(const float4*)(base + kk + 4);
            int4 o;
            o.x = pk2bf(v0.x, v0.y); o.y = pk2bf(v0.z, v0.w);
            o.z = pk2bf(v1.x, v1.y); o.w = pk2bf(v1.z, v1.w);
            *(int4*)&sAB[m][kc + kk] = o;
        }
    }
    if (t < 96) {
        const int m = t / 3, cc = t - m * 3;
        const int i = node0 + m;
        const float cnt = (float)deg[i];
        out_x[(size_t)i * 3 + cc] =
            coord[(size_t)i * 3 + cc] + __fdividef(xs[(size_t)i * 4 + cc], fmaxf(cnt, 1.0f));
    }
    __syncthreads();

    const int w = t >> 6, l = t & 63, c = l & 15, quad = l >> 4;
    const int n0 = w * 32;

    // GEMM1: M=32, K=256, N=128
    {
        f32x4 acc[2][2];
#pragma unroll
        for (int mt = 0; mt < 2; mt++)
#pragma unroll
            for (int tl = 0; tl < 2; tl++) acc[mt][tl] = (f32x4){0.f, 0.f, 0.f, 0.f};
#pragma unroll
        for (int k0 = 0; k0 < 256; k0 += 32) {
            const short8 a0 = *(const short8*)&sAB[c][k0 + quad * 8];
            const short8 a1 = *(const short8*)&sAB[16 + c][k0 + quad * 8];
#pragma unroll
            for (int tl = 0; tl < 2; tl++) {
                const short8 b = *(const short8*)(Wt_n1 +
                    ((size_t)(n0 + tl * 16 + c) << 8) + k0 + quad * 8);
                acc[0][tl] = __builtin_amdgcn_mfma_f32_16x16x32_bf16(a0, b, acc[0][tl], 0, 0, 0);
                acc[1][tl] = __builtin_amdgcn_mfma_f32_16x16x32_bf16(a1, b, acc[1][tl], 0, 0, 0);
            }
        }
#pragma unroll
        for (int mt = 0; mt < 2; mt++)
#pragma unroll
            for (int tl = 0; tl < 2; tl++) {
                const int col = n0 + tl * 16 + c;
                const float bb = bn1[col];
                const unsigned p01 = pk2bf(silu(acc[mt][tl][0] + bb), silu(acc[mt][tl][1] + bb));
                const unsigned p23 = pk2bf(silu(acc[mt][tl][2] + bb), silu(acc[mt][tl][3] + bb));
                const int row = mt * 16 + quad * 4;
                sH[row + 0][col] = (unsigned short)p01;
                sH[row + 1][col] = (unsigned short)(p01 >> 16);
                sH[row + 2][col] = (unsigned short)p23;
                sH[row + 3][col] = (unsigned short)(p23 >> 16);
            }
    }
    __syncthreads();

    // GEMM2: M=32, K=128, N=128
    {
        f32x4 acc[2][2];
#pragma unroll
        for (int mt = 0; mt < 2; mt++)
#pragma unroll
            for (int tl = 0; tl < 2; tl++) acc[mt][tl] = (f32x4){0.f, 0.f, 0.f, 0.f};
#pragma unroll
        for (int k0 = 0; k0 < 128; k0 += 32) {
            const short8 a0 = *(const short8*)&sH[c][k0 + quad * 8];
            const short8 a1 = *(const short8*)&sH[16 + c][k0 + quad * 8];
#pragma unroll
            for (int tl = 0; tl < 2; tl++) {
                const short8 b = *(const short8*)(Wt_n2 +
                    ((size_t)(n0 + tl * 16 + c) << 7) + k0 + quad * 8);
                acc[0][tl] = __builtin_amdgcn_mfma_f32_16x16x32_bf16(a0, b, acc[0][tl], 0, 0, 0);
                acc[1][tl] = __builtin_amdgcn_mfma_f32_16x16x32_bf16(a1, b, acc[1][tl], 0, 0, 0);
            }
        }
#pragma unroll
        for (int mt = 0; mt < 2; mt++)
#pragma unroll
            for (int tl = 0; tl < 2; tl++) {
                const int col = n0 + tl * 16 + c;
                const float bb = bn2[col];
#pragma unroll
                for (int r = 0; r < 4; r++) {
                    const int row = mt * 16 + quad * 4 + r;
                    out_h[(size_t)(node0 + row) * 128 + col] = acc[mt][tl][r] + bb;
                }
            }
    }
}

// ---------------------------------------------------------------------------
extern "C" void kernel_launch(void* const* d_in, const int* in_sizes, int n_in,
                              void* d_out, int out_size, void* d_ws, size_t ws_size,
                              hipStream_t stream) {
    const float* nf    = (const float*)d_in[0];
    const float* coord = (const float*)d_in[1];
    const int*   src   = (const int*)d_in[2];
    const int*   dst   = (const int*)d_in[3];
    const float* We1   = (const float*)d_in[4];
    const float* be1   = (const float*)d_in[5];
    const float* We2   = (const float*)d_in[6];
    const float* be2   = (const float*)d_in[7];
    const float* Wn1   = (const float*)d_in[8];
    const float* bn1   = (const float*)d_in[9];
    const float* Wn2   = (const float*)d_in[10];
    const float* bn2   = (const float*)d_in[11];
    const float* Wc1   = (const float*)d_in[12];
    const float* bc1   = (const float*)d_in[13];
    const float* Wc2   = (const float*)d_in[14];

    unsigned short* Pc = (unsigned short*)d_ws;            // N*256 bf16
    float* hn = (float*)(Pc + (size_t)N_NODES * 256);      // N*128 f32
    float* xs = hn + (size_t)N_NODES * 128;                // N*4
    int* deg       = (int*)(xs + (size_t)N_NODES * 4);     // N
    int* rsl       = deg + N_NODES;                        // N (block-local excl scan)
    int* cursor    = rsl + N_NODES;                        // N
    int* btot      = cursor + N_NODES;                     // 64
    int* elist     = btot + 64;                            // E
    unsigned short* Wt_e1 = (unsigned short*)
        (((uintptr_t)(elist + N_EDGES) + 255) & ~(uintptr_t)255);  // 256*128
    unsigned short* Wt_e2 = Wt_e1 + 256 * 128;                     // 128*128
    unsigned short* Wt_c1 = Wt_e2 + 128 * 128;                     // 128*128
    unsigned short* Wt_n1 = Wt_c1 + 128 * 128;                     // 128*256
    unsigned short* Wt_n2 = Wt_n1 + 128 * 256;                     // 128*128

    float* out_h = (float*)d_out;                          // N*128
    float* out_x = out_h + (size_t)N_NODES * 128;          // N*3

    k_pack2<<<256, 128, 0, stream>>>(We1, We2, Wc1, Wn1, Wn2,
                                     Wt_e1, Wt_e2, Wt_c1, Wt_n1, Wt_n2,
                                     deg, cursor, xs, hn);
    k_cntpre<<<N_NODES / 32, 256, 0, stream>>>(nf, Wt_e1, be1, Pc, dst, deg);
    k_scanA<<<40, 1024, 0, stream>>>(deg, rsl, btot);
    k_fill<<<(N_EDGES + 255) / 256, 256, 0, stream>>>(dst, rsl, btot, cursor, elist);
    k_edge10<<<N_EDGES / 64, 256, 0, stream>>>(Pc, coord, src, dst, elist,
                                               We1, Wt_e2, be2, Wt_c1, bc1,
                                               Wc2, hn, xs);
    k_node<<<N_NODES / 32, 256, 0, stream>>>(nf, coord, hn, xs, deg,
                                             Wt_n1, bn1, Wt_n2, bn2, out_h, out_x);
}

// Round 10
// 420.510 us; speedup vs baseline: 1.3159x; 1.3159x over previous
//
#include <hip/hip_runtime.h>
#include <hip/hip_bf16.h>
#include <math.h>
#include <stdint.h>

#define N_NODES 40000
#define N_EDGES 640000

typedef short short8 __attribute__((ext_vector_type(8)));
typedef float f32x4 __attribute__((ext_vector_type(4)));

__device__ __forceinline__ float silu(float x) {
    return __fdividef(x, 1.0f + __expf(-x));
}

__device__ __forceinline__ unsigned short f2bf(float f) {
    unsigned u = __float_as_uint(f);
    u += 0x7FFF + ((u >> 16) & 1);
    return (unsigned short)(u >> 16);
}
__device__ __forceinline__ float bf2f(unsigned short h) {
    return __uint_as_float(((unsigned)h) << 16);
}
__device__ __forceinline__ unsigned pk2bf(float a, float b) {
    __hip_bfloat162 h = __float22bfloat162_rn(make_float2(a, b));
    unsigned u;
    __builtin_memcpy(&u, &h, 4);
    return u;
}

// ---------------------------------------------------------------------------
// k_scanA: 40 blocks x 1024 threads; block b does an EXCLUSIVE scan of
// deg[b*1000 .. b*1000+999] -> rsl, and writes its block total to btot[b].
// ---------------------------------------------------------------------------
__global__ __launch_bounds__(1024) void k_scanA(const int* __restrict__ deg,
                                                int* __restrict__ rsl,
                                                int* __restrict__ btot) {
    __shared__ int wsum[16];
    const int t = threadIdx.x;
    const int lane = t & 63, wid = t >> 6;
    const int base = blockIdx.x * 1000;
    const int x0 = (t < 1000) ? deg[base + t] : 0;
    int x = x0;
#pragma unroll
    for (int s = 1; s < 64; s <<= 1) {
        const int u = __shfl_up(x, s, 64);
        if (lane >= s) x += u;
    }
    if (lane == 63) wsum[wid] = x;
    __syncthreads();
    if (wid == 0) {
        int ws = (lane < 16) ? wsum[lane] : 0;
#pragma unroll
        for (int s = 1; s < 16; s <<= 1) {
            const int u = __shfl_up(ws, s, 64);
            if (lane >= s) ws += u;
        }
        if (lane < 16) wsum[lane] = ws;
    }
    __syncthreads();
    const int wbase = (wid > 0) ? wsum[wid - 1] : 0;
    if (t < 1000) rsl[base + t] = wbase + x - x0;   // exclusive within block
    if (t == 0) btot[blockIdx.x] = wsum[15];
}

// ---------------------------------------------------------------------------
// k_fill: scanB FUSED — wave 0 of each block redundantly scans the 40 block
// totals (trivial) into LDS, then global CSR pos = sbo[d/1000]+rsl[d]+cursor.
// ---------------------------------------------------------------------------
__global__ __launch_bounds__(256) void k_fill(const int* __restrict__ dst,
                                              const int* __restrict__ rsl,
                                              const int* __restrict__ btot,
                                              int* __restrict__ cursor,
                                              int* __restrict__ elist) {
    __shared__ int sbo[40];
    const int t = threadIdx.x;
    if (t < 64) {
        const int x0 = (t < 40) ? btot[t] : 0;
        int x = x0;
#pragma unroll
        for (int s = 1; s < 64; s <<= 1) {
            const int u = __shfl_up(x, s, 64);
            if (t >= s) x += u;
        }
        if (t < 40) sbo[t] = x - x0;
    }
    __syncthreads();
    const int e = blockIdx.x * 256 + t;
    if (e < N_EDGES) {
        const int d = dst[e];
        const int p = atomicAdd(&cursor[d], 1);
        elist[sbo[d / 1000] + rsl[d] + p] = e;
    }
}

// ---------------------------------------------------------------------------
// k_pack2: bf16-transposed weight packs + folded memsets (deg/cursor/xs/hn).
// ---------------------------------------------------------------------------
__global__ __launch_bounds__(128) void k_pack2(
    const float* __restrict__ We1, const float* __restrict__ We2,
    const float* __restrict__ Wc1, const float* __restrict__ Wn1,
    const float* __restrict__ Wn2,
    unsigned short* __restrict__ Wt_e1, unsigned short* __restrict__ Wt_e2,
    unsigned short* __restrict__ Wt_c1, unsigned short* __restrict__ Wt_n1,
    unsigned short* __restrict__ Wt_n2,
    int* __restrict__ deg, int* __restrict__ cursor, float* __restrict__ xs,
    float* __restrict__ hn) {
    const int b = blockIdx.x;   // 0..255
    const int t = threadIdx.x;  // 0..127
    Wt_e1[b * 128 + t] = f2bf(We1[(size_t)((b >> 7) * 128 + t) * 128 + (b & 127)]);
    if (b < 128) {
        Wt_e2[b * 128 + t] = f2bf(We2[(size_t)t * 128 + b]);
        Wt_c1[b * 128 + t] = f2bf(Wc1[(size_t)t * 128 + b]);
        Wt_n2[b * 128 + t] = f2bf(Wn2[(size_t)t * 128 + b]);
        Wt_n1[b * 256 + t] = f2bf(Wn1[(size_t)t * 128 + b]);
        Wt_n1[b * 256 + 128 + t] = f2bf(Wn1[(size_t)(128 + t) * 128 + b]);
    }
    const int gid = b * 128 + t;                   // 0..32767
    for (int i = gid; i < N_NODES; i += 32768) { deg[i] = 0; cursor[i] = 0; }
    for (int i = gid; i < N_NODES * 4; i += 32768) xs[i] = 0.0f;
    float4* hz = (float4*)hn;
    const float4 z4 = {0.f, 0.f, 0.f, 0.f};
    for (int i = gid; i < N_NODES * 32; i += 32768) hz[i] = z4;
}

// ---------------------------------------------------------------------------
// k_cntpre: dst-degree histogram fused with Pc = nf @ [We1a|We1b] (bf16).
// be1 is BAKED into the dst half (cols 128..255) so k_edge9 skips the add.
// ---------------------------------------------------------------------------
__global__ __launch_bounds__(256) void k_cntpre(
    const float* __restrict__ nf, const unsigned short* __restrict__ Wt_e1,
    const float* __restrict__ be1,
    unsigned short* __restrict__ Pc,
    const int* __restrict__ dst, int* __restrict__ deg) {
    __shared__ __align__(16) unsigned short sNF[32][136];
    const int t = threadIdx.x;
    const int node0 = blockIdx.x * 32;
    {
        const int e0 = (blockIdx.x * 256 + t) * 2;
        const int d0 = dst[e0], d1 = dst[e0 + 1];
        atomicAdd(&deg[d0], 1);
        atomicAdd(&deg[d1], 1);
    }
    {
        const int m = t >> 3, kc = (t & 7) * 16;
        const float* sp = &nf[(size_t)(node0 + m) * 128 + kc];
        const float4 v0 = *(const float4*)(sp + 0);
        const float4 v1 = *(const float4*)(sp + 4);
        const float4 v2 = *(const float4*)(sp + 8);
        const float4 v3 = *(const float4*)(sp + 12);
        int4 o0, o1;
        o0.x = pk2bf(v0.x, v0.y); o0.y = pk2bf(v0.z, v0.w);
        o0.z = pk2bf(v1.x, v1.y); o0.w = pk2bf(v1.z, v1.w);
        o1.x = pk2bf(v2.x, v2.y); o1.y = pk2bf(v2.z, v2.w);
        o1.z = pk2bf(v3.x, v3.y); o1.w = pk2bf(v3.z, v3.w);
        *(int4*)&sNF[m][kc] = o0;
        *(int4*)&sNF[m][kc + 8] = o1;
    }
    __syncthreads();

    const int w = t >> 6, l = t & 63, c = l & 15, quad = l >> 4;
    const int n0 = w * 64;

    f32x4 acc[2][4];
#pragma unroll
    for (int mt = 0; mt < 2; mt++)
#pragma unroll
        for (int tl = 0; tl < 4; tl++) acc[mt][tl] = (f32x4){0.f, 0.f, 0.f, 0.f};

    __builtin_amdgcn_s_setprio(1);
#pragma unroll
    for (int k0 = 0; k0 < 128; k0 += 32) {
        const short8 a0 = *(const short8*)&sNF[c][k0 + quad * 8];
        const short8 a1 = *(const short8*)&sNF[16 + c][k0 + quad * 8];
#pragma unroll
        for (int tl = 0; tl < 4; tl++) {
            const short8 b = *(const short8*)(Wt_e1 +
                ((size_t)(n0 + tl * 16 + c) << 7) + k0 + quad * 8);
            acc[0][tl] = __builtin_amdgcn_mfma_f32_16x16x32_bf16(a0, b, acc[0][tl], 0, 0, 0);
            acc[1][tl] = __builtin_amdgcn_mfma_f32_16x16x32_bf16(a1, b, acc[1][tl], 0, 0, 0);
        }
    }
    __builtin_amdgcn_s_setprio(0);
#pragma unroll
    for (int mt = 0; mt < 2; mt++)
#pragma unroll
        for (int tl = 0; tl < 4; tl++) {
            const int col = n0 + tl * 16 + c;
            const float bias = (col >= 128) ? be1[col - 128] : 0.0f;
            const unsigned p01 = pk2bf(acc[mt][tl][0] + bias, acc[mt][tl][1] + bias);
            const unsigned p23 = pk2bf(acc[mt][tl][2] + bias, acc[mt][tl][3] + bias);
            const int row = node0 + mt * 16 + quad * 4;
            Pc[(size_t)(row + 0) * 256 + col] = (unsigned short)p01;
            Pc[(size_t)(row + 1) * 256 + col] = (unsigned short)(p01 >> 16);
            Pc[(size_t)(row + 2) * 256 + col] = (unsigned short)p23;
            Pc[(size_t)(row + 3) * 256 + col] = (unsigned short)(p23 >> 16);
        }
}

// ---------------------------------------------------------------------------
// k_edge9 (round-8 validated, 241.5us) + s_setprio around MFMA K-loops (T5:
// mixed-phase multi-block regime — scatter waves and MFMA waves co-resident).
// 64 edges / 256 threads / 4 waves, LDS 19.97KB -> 8 blocks/CU, be1 baked
// in Pc, bijective XCD chunking, 2-chain h-scatter, suffix-sum x-scatter.
// ---------------------------------------------------------------------------
__global__ __launch_bounds__(256) void k_edge9(
    const unsigned short* __restrict__ Pc, const float* __restrict__ coord,
    const int* __restrict__ src, const int* __restrict__ dst,
    const int* __restrict__ elist,
    const float* __restrict__ We1,
    const unsigned short* __restrict__ Wt_e2, const float* __restrict__ be2,
    const unsigned short* __restrict__ Wt_c1, const float* __restrict__ bc1,
    const float* __restrict__ Wc2,
    float* __restrict__ h_neigh, float* __restrict__ xs) {
    __shared__ __align__(16) unsigned short sT[64][136];   // 17408 B
    __shared__ float scoefp[4][32];                        // 512 B
    __shared__ float sw[128];                              // 512 B
    __shared__ float sdist[64];                            // 256 B
    __shared__ float sxd[64][3];                           // 768 B
    __shared__ int ssrc[64];                               // 256 B
    __shared__ int sdst[64];                               // 256 B  => 19968 B

    const int t = threadIdx.x;
    const int bid = (int)blockIdx.x;
    const int swz = (bid & 7) * 1250 + (bid >> 3);
    const int e0 = swz * 64;

    if (t < 64) {
        const int eid = elist[e0 + t];
        const int s = src[eid], d = dst[eid];
        ssrc[t] = s; sdst[t] = d;
        const float dx = coord[3 * s + 0] - coord[3 * d + 0];
        const float dy = coord[3 * s + 1] - coord[3 * d + 1];
        const float dz = coord[3 * s + 2] - coord[3 * d + 2];
        const float dist = sqrtf(dx * dx + dy * dy + dz * dz);
        sdist[t] = dist;
        const float inv = __fdividef(1.0f, dist + 1e-7f);
        sxd[t][0] = dx * inv; sxd[t][1] = dy * inv; sxd[t][2] = dz * inv;
    } else if (t < 96) {
        ((float4*)sw)[t - 64] = ((const float4*)(We1 + 256 * 128))[t - 64];
    }
    __syncthreads();   // B0

    // ---- t1 = silu(P1[s] + (P2[d]+be1) + dist*We1d): 4 lanes/edge ----
    {
        const int e = t >> 2;
        const int kc = (t & 3) * 32;
        const int s = ssrc[e], d = sdst[e];
        const float dist = sdist[e];
        const unsigned short* p1 = Pc + (size_t)s * 256 + kc;
        const unsigned short* p2 = Pc + (size_t)d * 256 + 128 + kc;
        short8 a[4], b[4];
#pragma unroll
        for (int i = 0; i < 4; i++) {
            a[i] = *(const short8*)(p1 + i * 8);
            b[i] = *(const short8*)(p2 + i * 8);
        }
#pragma unroll
        for (int i = 0; i < 4; i++) {
            float v[8];
#pragma unroll
            for (int kk = 0; kk < 8; kk++) {
                const int k = kc + i * 8 + kk;
                v[kk] = silu(bf2f((unsigned short)a[i][kk]) + bf2f((unsigned short)b[i][kk])
                             + dist * sw[k]);
            }
            int4 o;
            o.x = pk2bf(v[0], v[1]); o.y = pk2bf(v[2], v[3]);
            o.z = pk2bf(v[4], v[5]); o.w = pk2bf(v[6], v[7]);
            *(int4*)&sT[e][kc + i * 8] = o;
        }
    }
    __syncthreads();   // B1

    const int w = t >> 6;
    const int l = t & 63;
    const int h = w & 1;       // 32-edge group
    const int H = w >> 1;      // col half
    const int m0 = h * 32;
    const int n0 = H * 64;
    const int c = l & 15;
    const int quad = l >> 4;

    // ---- GEMM1 K-loop: acc = t1 @ We2 (M=32/wave, N=64) ----
    f32x4 acc1[2][4];
#pragma unroll
    for (int mt = 0; mt < 2; mt++)
#pragma unroll
        for (int tile = 0; tile < 4; tile++) acc1[mt][tile] = (f32x4){0.f, 0.f, 0.f, 0.f};
    __builtin_amdgcn_s_setprio(1);
#pragma unroll
    for (int k0 = 0; k0 < 128; k0 += 32) {
        const short8 a0 = *(const short8*)&sT[m0 + c][k0 + quad * 8];
        const short8 a1 = *(const short8*)&sT[m0 + 16 + c][k0 + quad * 8];
#pragma unroll
        for (int tile = 0; tile < 4; tile++) {
            const short8 b = *(const short8*)(Wt_e2 +
                ((size_t)(n0 + tile * 16 + c) << 7) + k0 + quad * 8);
            acc1[0][tile] = __builtin_amdgcn_mfma_f32_16x16x32_bf16(a0, b, acc1[0][tile], 0, 0, 0);
            acc1[1][tile] = __builtin_amdgcn_mfma_f32_16x16x32_bf16(a1, b, acc1[1][tile], 0, 0, 0);
        }
    }
    __builtin_amdgcn_s_setprio(0);
    __syncthreads();   // B2: all waves done reading t1 before overwrite

    // ---- epilogue: t2 = silu(acc + be2) written IN PLACE over t1 ----
#pragma unroll
    for (int mt = 0; mt < 2; mt++)
#pragma unroll
        for (int tile = 0; tile < 4; tile++) {
            const int col = n0 + tile * 16 + c;
            const float bb = be2[col];
            const unsigned p01 = pk2bf(silu(acc1[mt][tile][0] + bb), silu(acc1[mt][tile][1] + bb));
            const unsigned p23 = pk2bf(silu(acc1[mt][tile][2] + bb), silu(acc1[mt][tile][3] + bb));
            const int row = m0 + mt * 16 + quad * 4;
            sT[row + 0][col] = (unsigned short)p01;
            sT[row + 1][col] = (unsigned short)(p01 >> 16);
            sT[row + 2][col] = (unsigned short)p23;
            sT[row + 3][col] = (unsigned short)(p23 >> 16);
        }
    __syncthreads();   // B3

    // ---- h-scatter: two independent 16-row chains (2x ILP), atomics
    //      drain under GEMM2's compute ----
    {
        const int j = t & 127;
        const int q = t >> 7;     // 0..1: two 32-edge groups
        const int eb = q * 32;
        float aA = bf2f(sT[eb][j]);      int pA = sdst[eb];
        float aB = bf2f(sT[eb + 16][j]); int pB = sdst[eb + 16];
#pragma unroll
        for (int i = 1; i < 16; i++) {
            const int dA = sdst[eb + i];
            const int dB = sdst[eb + 16 + i];
            const float vA = bf2f(sT[eb + i][j]);
            const float vB = bf2f(sT[eb + 16 + i][j]);
            if (dA != pA) { atomicAdd(&h_neigh[(size_t)pA * 128 + j], aA); aA = 0.f; pA = dA; }
            aA += vA;
            if (dB != pB) { atomicAdd(&h_neigh[(size_t)pB * 128 + j], aB); aB = 0.f; pB = dB; }
            aB += vB;
        }
        atomicAdd(&h_neigh[(size_t)pA * 128 + j], aA);
        atomicAdd(&h_neigh[(size_t)pB * 128 + j], aB);
    }

    // ---- GEMM2: coef = silu(t2 @ Wc1 + bc1) . Wc2 ----
    {
        f32x4 acc[2][4];
#pragma unroll
        for (int mt = 0; mt < 2; mt++)
#pragma unroll
            for (int tile = 0; tile < 4; tile++) acc[mt][tile] = (f32x4){0.f, 0.f, 0.f, 0.f};
        __builtin_amdgcn_s_setprio(1);
#pragma unroll
        for (int k0 = 0; k0 < 128; k0 += 32) {
            const short8 a0 = *(const short8*)&sT[m0 + c][k0 + quad * 8];
            const short8 a1 = *(const short8*)&sT[m0 + 16 + c][k0 + quad * 8];
#pragma unroll
            for (int tile = 0; tile < 4; tile++) {
                const short8 b = *(const short8*)(Wt_c1 +
                    ((size_t)(n0 + tile * 16 + c) << 7) + k0 + quad * 8);
                acc[0][tile] = __builtin_amdgcn_mfma_f32_16x16x32_bf16(a0, b, acc[0][tile], 0, 0, 0);
                acc[1][tile] = __builtin_amdgcn_mfma_f32_16x16x32_bf16(a1, b, acc[1][tile], 0, 0, 0);
            }
        }
        __builtin_amdgcn_s_setprio(0);
        float part[2][4] = {{0.f, 0.f, 0.f, 0.f}, {0.f, 0.f, 0.f, 0.f}};
#pragma unroll
        for (int tile = 0; tile < 4; tile++) {
            const int col = n0 + tile * 16 + c;
            const float bc = bc1[col];
            const float wc = Wc2[col];
#pragma unroll
            for (int mt = 0; mt < 2; mt++)
#pragma unroll
                for (int r = 0; r < 4; r++)
                    part[mt][r] += silu(acc[mt][tile][r] + bc) * wc;
        }
#pragma unroll
        for (int off = 1; off < 16; off <<= 1) {
#pragma unroll
            for (int mt = 0; mt < 2; mt++)
#pragma unroll
                for (int r = 0; r < 4; r++)
                    part[mt][r] += __shfl_xor(part[mt][r], off, 64);
        }
        if (c == 0) {
#pragma unroll
            for (int mt = 0; mt < 2; mt++)
#pragma unroll
                for (int r = 0; r < 4; r++)
                    scoefp[w][mt * 16 + quad * 4 + r] = part[mt][r];
        }
    }

    // ---- x-scatter: 32-lane segmented suffix-sum over dst-sorted runs;
    //      run-head lanes emit atomics (partial coefs; atomics sum the two
    //      col-half waves' contributions). ----
    if (l < 32) {
        const int e = h * 32 + l;
        const int d = sdst[e];
        const float cf = scoefp[w][l];
        float v0 = cf * sxd[e][0];
        float v1 = cf * sxd[e][1];
        float v2 = cf * sxd[e][2];
#pragma unroll
        for (int s = 1; s < 32; s <<= 1) {
            const float u0 = __shfl_down(v0, s, 64);
            const float u1 = __shfl_down(v1, s, 64);
            const float u2 = __shfl_down(v2, s, 64);
            const int ud = __shfl_down(d, s, 64);
            if (l + s < 32 && ud == d) { v0 += u0; v1 += u1; v2 += u2; }
        }
        if (l == 0 || sdst[e - 1] != d) {
            atomicAdd(&xs[(size_t)d * 4 + 0], v0);
            atomicAdd(&xs[(size_t)d * 4 + 1], v1);
            atomicAdd(&xs[(size_t)d * 4 + 2], v2);
        }
    }
}

// ---------------------------------------------------------------------------
// k_node (MFMA): h = silu([nf|hn] @ Wn1 + bn1) @ Wn2 + bn2 ; x = coord+xs/cnt
// cnt comes straight from deg.
// ---------------------------------------------------------------------------
__global__ __launch_bounds__(256) void k_node(
    const float* __restrict__ nf, const float* __restrict__ coord,
    const float* __restrict__ hn, const float* __restrict__ xs,
    const int* __restrict__ deg,
    const unsigned short* __restrict__ Wt_n1, const float* __restrict__ bn1,
    const unsigned short* __restrict__ Wt_n2, const float* __restrict__ bn2,
    float* __restrict__ out_h, float* __restrict__ out_x) {
    __shared__ __align__(16) unsigned short sAB[32][264];
    __shared__ __align__(16) unsigned short sH[32][136];
    const int t = threadIdx.x;
    const int node0 = blockIdx.x * 32;
    {
        const int m = t >> 3, kc = (t & 7) * 32;
        const float* base = (kc < 128) ? &nf[(size_t)(node0 + m) * 128 + kc]
                                       : &hn[(size_t)(node0 + m) * 128 + (kc - 128)];
#pragma unroll
        for (int kk = 0; kk < 32; kk += 8) {
            const float4 v0 = *(const float4*)(base + kk);
            const float4 v1 = *(const float4*)(base + kk + 4);
            int4 o;
            o.x = pk2bf(v0.x, v0.y); o.y = pk2bf(v0.z, v0.w);
            o.z = pk2bf(v1.x, v1.y); o.w = pk2bf(v1.z, v1.w);
            *(int4*)&sAB[m][kc + kk] = o;
        }
    }
    if (t < 96) {
        const int m = t / 3, cc = t - m * 3;
        const int i = node0 + m;
        const float cnt = (float)deg[i];
        out_x[(size_t)i * 3 + cc] =
            coord[(size_t)i * 3 + cc] + __fdividef(xs[(size_t)i * 4 + cc], fmaxf(cnt, 1.0f));
    }
    __syncthreads();

    const int w = t >> 6, l = t & 63, c = l & 15, quad = l >> 4;
    const int n0 = w * 32;

    // GEMM1: M=32, K=256, N=128
    {
        f32x4 acc[2][2];
#pragma unroll
        for (int mt = 0; mt < 2; mt++)
#pragma unroll
            for (int tl = 0; tl < 2; tl++) acc[mt][tl] = (f32x4){0.f, 0.f, 0.f, 0.f};
        __builtin_amdgcn_s_setprio(1);
#pragma unroll
        for (int k0 = 0; k0 < 256; k0 += 32) {
            const short8 a0 = *(const short8*)&sAB[c][k0 + quad * 8];
            const short8 a1 = *(const short8*)&sAB[16 + c][k0 + quad * 8];
#pragma unroll
            for (int tl = 0; tl < 2; tl++) {
                const short8 b = *(const short8*)(Wt_n1 +
                    ((size_t)(n0 + tl * 16 + c) << 8) + k0 + quad * 8);
                acc[0][tl] = __builtin_amdgcn_mfma_f32_16x16x32_bf16(a0, b, acc[0][tl], 0, 0, 0);
                acc[1][tl] = __builtin_amdgcn_mfma_f32_16x16x32_bf16(a1, b, acc[1][tl], 0, 0, 0);
            }
        }
        __builtin_amdgcn_s_setprio(0);
#pragma unroll
        for (int mt = 0; mt < 2; mt++)
#pragma unroll
            for (int tl = 0; tl < 2; tl++) {
                const int col = n0 + tl * 16 + c;
                const float bb = bn1[col];
                const unsigned p01 = pk2bf(silu(acc[mt][tl][0] + bb), silu(acc[mt][tl][1] + bb));
                const unsigned p23 = pk2bf(silu(acc[mt][tl][2] + bb), silu(acc[mt][tl][3] + bb));
                const int row = mt * 16 + quad * 4;
                sH[row + 0][col] = (unsigned short)p01;
                sH[row + 1][col] = (unsigned short)(p01 >> 16);
                sH[row + 2][col] = (unsigned short)p23;
                sH[row + 3][col] = (unsigned short)(p23 >> 16);
            }
    }
    __syncthreads();

    // GEMM2: M=32, K=128, N=128
    {
        f32x4 acc[2][2];
#pragma unroll
        for (int mt = 0; mt < 2; mt++)
#pragma unroll
            for (int tl = 0; tl < 2; tl++) acc[mt][tl] = (f32x4){0.f, 0.f, 0.f, 0.f};
        __builtin_amdgcn_s_setprio(1);
#pragma unroll
        for (int k0 = 0; k0 < 128; k0 += 32) {
            const short8 a0 = *(const short8*)&sH[c][k0 + quad * 8];
            const short8 a1 = *(const short8*)&sH[16 + c][k0 + quad * 8];
#pragma unroll
            for (int tl = 0; tl < 2; tl++) {
                const short8 b = *(const short8*)(Wt_n2 +
                    ((size_t)(n0 + tl * 16 + c) << 7) + k0 + quad * 8);
                acc[0][tl] = __builtin_amdgcn_mfma_f32_16x16x32_bf16(a0, b, acc[0][tl], 0, 0, 0);
                acc[1][tl] = __builtin_amdgcn_mfma_f32_16x16x32_bf16(a1, b, acc[1][tl], 0, 0, 0);
            }
        }
        __builtin_amdgcn_s_setprio(0);
#pragma unroll
        for (int mt = 0; mt < 2; mt++)
#pragma unroll
            for (int tl = 0; tl < 2; tl++) {
                const int col = n0 + tl * 16 + c;
                const float bb = bn2[col];
#pragma unroll
                for (int r = 0; r < 4; r++) {
                    const int row = mt * 16 + quad * 4 + r;
                    out_h[(size_t)(node0 + row) * 128 + col] = acc[mt][tl][r] + bb;
                }
            }
    }
}

// ---------------------------------------------------------------------------
extern "C" void kernel_launch(void* const* d_in, const int* in_sizes, int n_in,
                              void* d_out, int out_size, void* d_ws, size_t ws_size,
                              hipStream_t stream) {
    const float* nf    = (const float*)d_in[0];
    const float* coord = (const float*)d_in[1];
    const int*   src   = (const int*)d_in[2];
    const int*   dst   = (const int*)d_in[3];
    const float* We1   = (const float*)d_in[4];
    const float* be1   = (const float*)d_in[5];
    const float* We2   = (const float*)d_in[6];
    const float* be2   = (const float*)d_in[7];
    const float* Wn1   = (const float*)d_in[8];
    const float* bn1   = (const float*)d_in[9];
    const float* Wn2   = (const float*)d_in[10];
    const float* bn2   = (const float*)d_in[11];
    const float* Wc1   = (const float*)d_in[12];
    const float* bc1   = (const float*)d_in[13];
    const float* Wc2   = (const float*)d_in[14];

    unsigned short* Pc = (unsigned short*)d_ws;            // N*256 bf16
    float* hn = (float*)(Pc + (size_t)N_NODES * 256);      // N*128 f32
    float* xs = hn + (size_t)N_NODES * 128;                // N*4
    int* deg       = (int*)(xs + (size_t)N_NODES * 4);     // N
    int* rsl       = deg + N_NODES;                        // N (block-local excl scan)
    int* cursor    = rsl + N_NODES;                        // N
    int* btot      = cursor + N_NODES;                     // 64
    int* elist     = btot + 64;                            // E
    unsigned short* Wt_e1 = (unsigned short*)
        (((uintptr_t)(elist + N_EDGES) + 255) & ~(uintptr_t)255);  // 256*128
    unsigned short* Wt_e2 = Wt_e1 + 256 * 128;                     // 128*128
    unsigned short* Wt_c1 = Wt_e2 + 128 * 128;                     // 128*128
    unsigned short* Wt_n1 = Wt_c1 + 128 * 128;                     // 128*256
    unsigned short* Wt_n2 = Wt_n1 + 128 * 256;                     // 128*128

    float* out_h = (float*)d_out;                          // N*128
    float* out_x = out_h + (size_t)N_NODES * 128;          // N*3

    k_pack2<<<256, 128, 0, stream>>>(We1, We2, Wc1, Wn1, Wn2,
                                     Wt_e1, Wt_e2, Wt_c1, Wt_n1, Wt_n2,
                                     deg, cursor, xs, hn);
    k_cntpre<<<N_NODES / 32, 256, 0, stream>>>(nf, Wt_e1, be1, Pc, dst, deg);
    k_scanA<<<40, 1024, 0, stream>>>(deg, rsl, btot);
    k_fill<<<(N_EDGES + 255) / 256, 256, 0, stream>>>(dst, rsl, btot, cursor, elist);
    k_edge9<<<N_EDGES / 64, 256, 0, stream>>>(Pc, coord, src, dst, elist,
                                              We1, Wt_e2, be2, Wt_c1, bc1,
                                              Wc2, hn, xs);
    k_node<<<N_NODES / 32, 256, 0, stream>>>(nf, coord, hn, xs, deg,
                                             Wt_n1, bn1, Wt_n2, bn2, out_h, out_x);
}

// Round 11
// 411.630 us; speedup vs baseline: 1.3443x; 1.0216x over previous
//
#include <hip/hip_runtime.h>
#include <hip/hip_bf16.h>
#include <math.h>
#include <stdint.h>

#define N_NODES 40000
#define N_EDGES 640000

typedef short short8 __attribute__((ext_vector_type(8)));
typedef float f32x4 __attribute__((ext_vector_type(4)));

__device__ __forceinline__ float silu(float x) {
    return __fdividef(x, 1.0f + __expf(-x));
}

__device__ __forceinline__ unsigned short f2bf(float f) {
    unsigned u = __float_as_uint(f);
    u += 0x7FFF + ((u >> 16) & 1);
    return (unsigned short)(u >> 16);
}
__device__ __forceinline__ float bf2f(unsigned short h) {
    return __uint_as_float(((unsigned)h) << 16);
}
__device__ __forceinline__ unsigned pk2bf(float a, float b) {
    __hip_bfloat162 h = __float22bfloat162_rn(make_float2(a, b));
    unsigned u;
    __builtin_memcpy(&u, &h, 4);
    return u;
}

// ---------------------------------------------------------------------------
// k_scanA: 40 blocks x 1024 threads; block b does an EXCLUSIVE scan of
// deg[b*1000 .. b*1000+999] -> rsl, and writes its block total to btot[b].
// ---------------------------------------------------------------------------
__global__ __launch_bounds__(1024) void k_scanA(const int* __restrict__ deg,
                                                int* __restrict__ rsl,
                                                int* __restrict__ btot) {
    __shared__ int wsum[16];
    const int t = threadIdx.x;
    const int lane = t & 63, wid = t >> 6;
    const int base = blockIdx.x * 1000;
    const int x0 = (t < 1000) ? deg[base + t] : 0;
    int x = x0;
#pragma unroll
    for (int s = 1; s < 64; s <<= 1) {
        const int u = __shfl_up(x, s, 64);
        if (lane >= s) x += u;
    }
    if (lane == 63) wsum[wid] = x;
    __syncthreads();
    if (wid == 0) {
        int ws = (lane < 16) ? wsum[lane] : 0;
#pragma unroll
        for (int s = 1; s < 16; s <<= 1) {
            const int u = __shfl_up(ws, s, 64);
            if (lane >= s) ws += u;
        }
        if (lane < 16) wsum[lane] = ws;
    }
    __syncthreads();
    const int wbase = (wid > 0) ? wsum[wid - 1] : 0;
    if (t < 1000) rsl[base + t] = wbase + x - x0;   // exclusive within block
    if (t == 0) btot[blockIdx.x] = wsum[15];
}

// ---------------------------------------------------------------------------
// k_fill: scanB FUSED — wave 0 of each block redundantly scans the 40 block
// totals (trivial) into LDS, then global CSR pos = sbo[d/1000]+rsl[d]+cursor.
// ---------------------------------------------------------------------------
__global__ __launch_bounds__(256) void k_fill(const int* __restrict__ dst,
                                              const int* __restrict__ rsl,
                                              const int* __restrict__ btot,
                                              int* __restrict__ cursor,
                                              int* __restrict__ elist) {
    __shared__ int sbo[40];
    const int t = threadIdx.x;
    if (t < 64) {
        const int x0 = (t < 40) ? btot[t] : 0;
        int x = x0;
#pragma unroll
        for (int s = 1; s < 64; s <<= 1) {
            const int u = __shfl_up(x, s, 64);
            if (t >= s) x += u;
        }
        if (t < 40) sbo[t] = x - x0;
    }
    __syncthreads();
    const int e = blockIdx.x * 256 + t;
    if (e < N_EDGES) {
        const int d = dst[e];
        const int p = atomicAdd(&cursor[d], 1);
        elist[sbo[d / 1000] + rsl[d] + p] = e;
    }
}

// ---------------------------------------------------------------------------
// k_pack2: bf16-transposed weight packs + folded memsets (deg/cursor/xs/hn).
// ---------------------------------------------------------------------------
__global__ __launch_bounds__(128) void k_pack2(
    const float* __restrict__ We1, const float* __restrict__ We2,
    const float* __restrict__ Wc1, const float* __restrict__ Wn1,
    const float* __restrict__ Wn2,
    unsigned short* __restrict__ Wt_e1, unsigned short* __restrict__ Wt_e2,
    unsigned short* __restrict__ Wt_c1, unsigned short* __restrict__ Wt_n1,
    unsigned short* __restrict__ Wt_n2,
    int* __restrict__ deg, int* __restrict__ cursor, float* __restrict__ xs,
    float* __restrict__ hn) {
    const int b = blockIdx.x;   // 0..255
    const int t = threadIdx.x;  // 0..127
    Wt_e1[b * 128 + t] = f2bf(We1[(size_t)((b >> 7) * 128 + t) * 128 + (b & 127)]);
    if (b < 128) {
        Wt_e2[b * 128 + t] = f2bf(We2[(size_t)t * 128 + b]);
        Wt_c1[b * 128 + t] = f2bf(Wc1[(size_t)t * 128 + b]);
        Wt_n2[b * 128 + t] = f2bf(Wn2[(size_t)t * 128 + b]);
        Wt_n1[b * 256 + t] = f2bf(Wn1[(size_t)t * 128 + b]);
        Wt_n1[b * 256 + 128 + t] = f2bf(Wn1[(size_t)(128 + t) * 128 + b]);
    }
    const int gid = b * 128 + t;                   // 0..32767
    for (int i = gid; i < N_NODES; i += 32768) { deg[i] = 0; cursor[i] = 0; }
    for (int i = gid; i < N_NODES * 4; i += 32768) xs[i] = 0.0f;
    float4* hz = (float4*)hn;
    const float4 z4 = {0.f, 0.f, 0.f, 0.f};
    for (int i = gid; i < N_NODES * 32; i += 32768) hz[i] = z4;
}

// ---------------------------------------------------------------------------
// k_cntpre: dst-degree histogram fused with Pc = nf @ [We1a|We1b] (bf16).
// 64 NODES/BLOCK (625 blocks): 2x MFMA per B-fragment load, half the launch
// ramp of the 1250-block version. Histogram: 4 edges/thread via int4.
// be1 is BAKED into the dst half (cols 128..255) so k_edge9 skips the add.
// ---------------------------------------------------------------------------
__global__ __launch_bounds__(256) void k_cntpre(
    const float* __restrict__ nf, const unsigned short* __restrict__ Wt_e1,
    const float* __restrict__ be1,
    unsigned short* __restrict__ Pc,
    const int* __restrict__ dst, int* __restrict__ deg) {
    __shared__ __align__(16) unsigned short sNF[64][136];
    const int t = threadIdx.x;
    const int node0 = blockIdx.x * 64;
    {
        const int e0 = (blockIdx.x * 256 + t) * 4;   // 625*256*4 == N_EDGES
        const int4 d4 = *(const int4*)(dst + e0);
        atomicAdd(&deg[d4.x], 1);
        atomicAdd(&deg[d4.y], 1);
        atomicAdd(&deg[d4.z], 1);
        atomicAdd(&deg[d4.w], 1);
    }
    {
        const int m = t >> 2, kc = (t & 3) * 32;     // 64 rows, 32 cols/thread
        const float* sp = &nf[(size_t)(node0 + m) * 128 + kc];
#pragma unroll
        for (int kk = 0; kk < 32; kk += 16) {
            const float4 v0 = *(const float4*)(sp + kk + 0);
            const float4 v1 = *(const float4*)(sp + kk + 4);
            const float4 v2 = *(const float4*)(sp + kk + 8);
            const float4 v3 = *(const float4*)(sp + kk + 12);
            int4 o0, o1;
            o0.x = pk2bf(v0.x, v0.y); o0.y = pk2bf(v0.z, v0.w);
            o0.z = pk2bf(v1.x, v1.y); o0.w = pk2bf(v1.z, v1.w);
            o1.x = pk2bf(v2.x, v2.y); o1.y = pk2bf(v2.z, v2.w);
            o1.z = pk2bf(v3.x, v3.y); o1.w = pk2bf(v3.z, v3.w);
            *(int4*)&sNF[m][kc + kk] = o0;
            *(int4*)&sNF[m][kc + kk + 8] = o1;
        }
    }
    __syncthreads();

    const int w = t >> 6, l = t & 63, c = l & 15, quad = l >> 4;
    const int n0 = w * 64;

    f32x4 acc[4][4];   // M=64 (4 m-tiles) x N=64 (4 tiles) per wave
#pragma unroll
    for (int mt = 0; mt < 4; mt++)
#pragma unroll
        for (int tl = 0; tl < 4; tl++) acc[mt][tl] = (f32x4){0.f, 0.f, 0.f, 0.f};

#pragma unroll
    for (int k0 = 0; k0 < 128; k0 += 32) {
        short8 a[4];
#pragma unroll
        for (int mt = 0; mt < 4; mt++)
            a[mt] = *(const short8*)&sNF[mt * 16 + c][k0 + quad * 8];
#pragma unroll
        for (int tl = 0; tl < 4; tl++) {
            const short8 b = *(const short8*)(Wt_e1 +
                ((size_t)(n0 + tl * 16 + c) << 7) + k0 + quad * 8);
#pragma unroll
            for (int mt = 0; mt < 4; mt++)
                acc[mt][tl] = __builtin_amdgcn_mfma_f32_16x16x32_bf16(a[mt], b, acc[mt][tl], 0, 0, 0);
        }
    }
#pragma unroll
    for (int mt = 0; mt < 4; mt++)
#pragma unroll
        for (int tl = 0; tl < 4; tl++) {
            const int col = n0 + tl * 16 + c;
            const float bias = (col >= 128) ? be1[col - 128] : 0.0f;
            const unsigned p01 = pk2bf(acc[mt][tl][0] + bias, acc[mt][tl][1] + bias);
            const unsigned p23 = pk2bf(acc[mt][tl][2] + bias, acc[mt][tl][3] + bias);
            const int row = node0 + mt * 16 + quad * 4;
            Pc[(size_t)(row + 0) * 256 + col] = (unsigned short)p01;
            Pc[(size_t)(row + 1) * 256 + col] = (unsigned short)(p01 >> 16);
            Pc[(size_t)(row + 2) * 256 + col] = (unsigned short)p23;
            Pc[(size_t)(row + 3) * 256 + col] = (unsigned short)(p23 >> 16);
        }
}

// ---------------------------------------------------------------------------
// k_edge9 (round-8 validated, 241.5us, setprio REVERTED — T5 cost ~8us in
// this barrier-lockstep regime): 64 edges / 256 threads / 4 waves,
// LDS 19.97KB -> 8 blocks/CU, be1 baked in Pc, bijective XCD chunking,
// 2-chain h-scatter, suffix-sum x-scatter.
// ---------------------------------------------------------------------------
__global__ __launch_bounds__(256) void k_edge9(
    const unsigned short* __restrict__ Pc, const float* __restrict__ coord,
    const int* __restrict__ src, const int* __restrict__ dst,
    const int* __restrict__ elist,
    const float* __restrict__ We1,
    const unsigned short* __restrict__ Wt_e2, const float* __restrict__ be2,
    const unsigned short* __restrict__ Wt_c1, const float* __restrict__ bc1,
    const float* __restrict__ Wc2,
    float* __restrict__ h_neigh, float* __restrict__ xs) {
    __shared__ __align__(16) unsigned short sT[64][136];   // 17408 B
    __shared__ float scoefp[4][32];                        // 512 B
    __shared__ float sw[128];                              // 512 B
    __shared__ float sdist[64];                            // 256 B
    __shared__ float sxd[64][3];                           // 768 B
    __shared__ int ssrc[64];                               // 256 B
    __shared__ int sdst[64];                               // 256 B  => 19968 B

    const int t = threadIdx.x;
    const int bid = (int)blockIdx.x;
    const int swz = (bid & 7) * 1250 + (bid >> 3);
    const int e0 = swz * 64;

    if (t < 64) {
        const int eid = elist[e0 + t];
        const int s = src[eid], d = dst[eid];
        ssrc[t] = s; sdst[t] = d;
        const float dx = coord[3 * s + 0] - coord[3 * d + 0];
        const float dy = coord[3 * s + 1] - coord[3 * d + 1];
        const float dz = coord[3 * s + 2] - coord[3 * d + 2];
        const float dist = sqrtf(dx * dx + dy * dy + dz * dz);
        sdist[t] = dist;
        const float inv = __fdividef(1.0f, dist + 1e-7f);
        sxd[t][0] = dx * inv; sxd[t][1] = dy * inv; sxd[t][2] = dz * inv;
    } else if (t < 96) {
        ((float4*)sw)[t - 64] = ((const float4*)(We1 + 256 * 128))[t - 64];
    }
    __syncthreads();   // B0

    // ---- t1 = silu(P1[s] + (P2[d]+be1) + dist*We1d): 4 lanes/edge ----
    {
        const int e = t >> 2;
        const int kc = (t & 3) * 32;
        const int s = ssrc[e], d = sdst[e];
        const float dist = sdist[e];
        const unsigned short* p1 = Pc + (size_t)s * 256 + kc;
        const unsigned short* p2 = Pc + (size_t)d * 256 + 128 + kc;
        short8 a[4], b[4];
#pragma unroll
        for (int i = 0; i < 4; i++) {
            a[i] = *(const short8*)(p1 + i * 8);
            b[i] = *(const short8*)(p2 + i * 8);
        }
#pragma unroll
        for (int i = 0; i < 4; i++) {
            float v[8];
#pragma unroll
            for (int kk = 0; kk < 8; kk++) {
                const int k = kc + i * 8 + kk;
                v[kk] = silu(bf2f((unsigned short)a[i][kk]) + bf2f((unsigned short)b[i][kk])
                             + dist * sw[k]);
            }
            int4 o;
            o.x = pk2bf(v[0], v[1]); o.y = pk2bf(v[2], v[3]);
            o.z = pk2bf(v[4], v[5]); o.w = pk2bf(v[6], v[7]);
            *(int4*)&sT[e][kc + i * 8] = o;
        }
    }
    __syncthreads();   // B1

    const int w = t >> 6;
    const int l = t & 63;
    const int h = w & 1;       // 32-edge group
    const int H = w >> 1;      // col half
    const int m0 = h * 32;
    const int n0 = H * 64;
    const int c = l & 15;
    const int quad = l >> 4;

    // ---- GEMM1 K-loop: acc = t1 @ We2 (M=32/wave, N=64) ----
    f32x4 acc1[2][4];
#pragma unroll
    for (int mt = 0; mt < 2; mt++)
#pragma unroll
        for (int tile = 0; tile < 4; tile++) acc1[mt][tile] = (f32x4){0.f, 0.f, 0.f, 0.f};
#pragma unroll
    for (int k0 = 0; k0 < 128; k0 += 32) {
        const short8 a0 = *(const short8*)&sT[m0 + c][k0 + quad * 8];
        const short8 a1 = *(const short8*)&sT[m0 + 16 + c][k0 + quad * 8];
#pragma unroll
        for (int tile = 0; tile < 4; tile++) {
            const short8 b = *(const short8*)(Wt_e2 +
                ((size_t)(n0 + tile * 16 + c) << 7) + k0 + quad * 8);
            acc1[0][tile] = __builtin_amdgcn_mfma_f32_16x16x32_bf16(a0, b, acc1[0][tile], 0, 0, 0);
            acc1[1][tile] = __builtin_amdgcn_mfma_f32_16x16x32_bf16(a1, b, acc1[1][tile], 0, 0, 0);
        }
    }
    __syncthreads();   // B2: all waves done reading t1 before overwrite

    // ---- epilogue: t2 = silu(acc + be2) written IN PLACE over t1 ----
#pragma unroll
    for (int mt = 0; mt < 2; mt++)
#pragma unroll
        for (int tile = 0; tile < 4; tile++) {
            const int col = n0 + tile * 16 + c;
            const float bb = be2[col];
            const unsigned p01 = pk2bf(silu(acc1[mt][tile][0] + bb), silu(acc1[mt][tile][1] + bb));
            const unsigned p23 = pk2bf(silu(acc1[mt][tile][2] + bb), silu(acc1[mt][tile][3] + bb));
            const int row = m0 + mt * 16 + quad * 4;
            sT[row + 0][col] = (unsigned short)p01;
            sT[row + 1][col] = (unsigned short)(p01 >> 16);
            sT[row + 2][col] = (unsigned short)p23;
            sT[row + 3][col] = (unsigned short)(p23 >> 16);
        }
    __syncthreads();   // B3

    // ---- h-scatter: two independent 16-row chains (2x ILP), atomics
    //      drain under GEMM2's compute ----
    {
        const int j = t & 127;
        const int q = t >> 7;     // 0..1: two 32-edge groups
        const int eb = q * 32;
        float aA = bf2f(sT[eb][j]);      int pA = sdst[eb];
        float aB = bf2f(sT[eb + 16][j]); int pB = sdst[eb + 16];
#pragma unroll
        for (int i = 1; i < 16; i++) {
            const int dA = sdst[eb + i];
            const int dB = sdst[eb + 16 + i];
            const float vA = bf2f(sT[eb + i][j]);
            const float vB = bf2f(sT[eb + 16 + i][j]);
            if (dA != pA) { atomicAdd(&h_neigh[(size_t)pA * 128 + j], aA); aA = 0.f; pA = dA; }
            aA += vA;
            if (dB != pB) { atomicAdd(&h_neigh[(size_t)pB * 128 + j], aB); aB = 0.f; pB = dB; }
            aB += vB;
        }
        atomicAdd(&h_neigh[(size_t)pA * 128 + j], aA);
        atomicAdd(&h_neigh[(size_t)pB * 128 + j], aB);
    }

    // ---- GEMM2: coef = silu(t2 @ Wc1 + bc1) . Wc2 ----
    {
        f32x4 acc[2][4];
#pragma unroll
        for (int mt = 0; mt < 2; mt++)
#pragma unroll
            for (int tile = 0; tile < 4; tile++) acc[mt][tile] = (f32x4){0.f, 0.f, 0.f, 0.f};
#pragma unroll
        for (int k0 = 0; k0 < 128; k0 += 32) {
            const short8 a0 = *(const short8*)&sT[m0 + c][k0 + quad * 8];
            const short8 a1 = *(const short8*)&sT[m0 + 16 + c][k0 + quad * 8];
#pragma unroll
            for (int tile = 0; tile < 4; tile++) {
                const short8 b = *(const short8*)(Wt_c1 +
                    ((size_t)(n0 + tile * 16 + c) << 7) + k0 + quad * 8);
                acc[0][tile] = __builtin_amdgcn_mfma_f32_16x16x32_bf16(a0, b, acc[0][tile], 0, 0, 0);
                acc[1][tile] = __builtin_amdgcn_mfma_f32_16x16x32_bf16(a1, b, acc[1][tile], 0, 0, 0);
            }
        }
        float part[2][4] = {{0.f, 0.f, 0.f, 0.f}, {0.f, 0.f, 0.f, 0.f}};
#pragma unroll
        for (int tile = 0; tile < 4; tile++) {
            const int col = n0 + tile * 16 + c;
            const float bc = bc1[col];
            const float wc = Wc2[col];
#pragma unroll
            for (int mt = 0; mt < 2; mt++)
#pragma unroll
                for (int r = 0; r < 4; r++)
                    part[mt][r] += silu(acc[mt][tile][r] + bc) * wc;
        }
#pragma unroll
        for (int off = 1; off < 16; off <<= 1) {
#pragma unroll
            for (int mt = 0; mt < 2; mt++)
#pragma unroll
                for (int r = 0; r < 4; r++)
                    part[mt][r] += __shfl_xor(part[mt][r], off, 64);
        }
        if (c == 0) {
#pragma unroll
            for (int mt = 0; mt < 2; mt++)
#pragma unroll
                for (int r = 0; r < 4; r++)
                    scoefp[w][mt * 16 + quad * 4 + r] = part[mt][r];
        }
    }

    // ---- x-scatter: 32-lane segmented suffix-sum over dst-sorted runs;
    //      run-head lanes emit atomics (partial coefs; atomics sum the two
    //      col-half waves' contributions). ----
    if (l < 32) {
        const int e = h * 32 + l;
        const int d = sdst[e];
        const float cf = scoefp[w][l];
        float v0 = cf * sxd[e][0];
        float v1 = cf * sxd[e][1];
        float v2 = cf * sxd[e][2];
#pragma unroll
        for (int s = 1; s < 32; s <<= 1) {
            const float u0 = __shfl_down(v0, s, 64);
            const float u1 = __shfl_down(v1, s, 64);
            const float u2 = __shfl_down(v2, s, 64);
            const int ud = __shfl_down(d, s, 64);
            if (l + s < 32 && ud == d) { v0 += u0; v1 += u1; v2 += u2; }
        }
        if (l == 0 || sdst[e - 1] != d) {
            atomicAdd(&xs[(size_t)d * 4 + 0], v0);
            atomicAdd(&xs[(size_t)d * 4 + 1], v1);
            atomicAdd(&xs[(size_t)d * 4 + 2], v2);
        }
    }
}

// ---------------------------------------------------------------------------
// k_node (MFMA): h = silu([nf|hn] @ Wn1 + bn1) @ Wn2 + bn2 ; x = coord+xs/cnt
// cnt comes straight from deg.
// ---------------------------------------------------------------------------
__global__ __launch_bounds__(256) void k_node(
    const float* __restrict__ nf, const float* __restrict__ coord,
    const float* __restrict__ hn, const float* __restrict__ xs,
    const int* __restrict__ deg,
    const unsigned short* __restrict__ Wt_n1, const float* __restrict__ bn1,
    const unsigned short* __restrict__ Wt_n2, const float* __restrict__ bn2,
    float* __restrict__ out_h, float* __restrict__ out_x) {
    __shared__ __align__(16) unsigned short sAB[32][264];
    __shared__ __align__(16) unsigned short sH[32][136];
    const int t = threadIdx.x;
    const int node0 = blockIdx.x * 32;
    {
        const int m = t >> 3, kc = (t & 7) * 32;
        const float* base = (kc < 128) ? &nf[(size_t)(node0 + m) * 128 + kc]
                                       : &hn[(size_t)(node0 + m) * 128 + (kc - 128)];
#pragma unroll
        for (int kk = 0; kk < 32; kk += 8) {
            const float4 v0 = *(const float4*)(base + kk);
            const float4 v1 = *(const float4*)(base + kk + 4);
            int4 o;
            o.x = pk2bf(v0.x, v0.y); o.y = pk2bf(v0.z, v0.w);
            o.z = pk2bf(v1.x, v1.y); o.w = pk2bf(v1.z, v1.w);
            *(int4*)&sAB[m][kc + kk] = o;
        }
    }
    if (t < 96) {
        const int m = t / 3, cc = t - m * 3;
        const int i = node0 + m;
        const float cnt = (float)deg[i];
        out_x[(size_t)i * 3 + cc] =
            coord[(size_t)i * 3 + cc] + __fdividef(xs[(size_t)i * 4 + cc], fmaxf(cnt, 1.0f));
    }
    __syncthreads();

    const int w = t >> 6, l = t & 63, c = l & 15, quad = l >> 4;
    const int n0 = w * 32;

    // GEMM1: M=32, K=256, N=128
    {
        f32x4 acc[2][2];
#pragma unroll
        for (int mt = 0; mt < 2; mt++)
#pragma unroll
            for (int tl = 0; tl < 2; tl++) acc[mt][tl] = (f32x4){0.f, 0.f, 0.f, 0.f};
#pragma unroll
        for (int k0 = 0; k0 < 256; k0 += 32) {
            const short8 a0 = *(const short8*)&sAB[c][k0 + quad * 8];
            const short8 a1 = *(const short8*)&sAB[16 + c][k0 + quad * 8];
#pragma unroll
            for (int tl = 0; tl < 2; tl++) {
                const short8 b = *(const short8*)(Wt_n1 +
                    ((size_t)(n0 + tl * 16 + c) << 8) + k0 + quad * 8);
                acc[0][tl] = __builtin_amdgcn_mfma_f32_16x16x32_bf16(a0, b, acc[0][tl], 0, 0, 0);
                acc[1][tl] = __builtin_amdgcn_mfma_f32_16x16x32_bf16(a1, b, acc[1][tl], 0, 0, 0);
            }
        }
#pragma unroll
        for (int mt = 0; mt < 2; mt++)
#pragma unroll
            for (int tl = 0; tl < 2; tl++) {
                const int col = n0 + tl * 16 + c;
                const float bb = bn1[col];
                const unsigned p01 = pk2bf(silu(acc[mt][tl][0] + bb), silu(acc[mt][tl][1] + bb));
                const unsigned p23 = pk2bf(silu(acc[mt][tl][2] + bb), silu(acc[mt][tl][3] + bb));
                const int row = mt * 16 + quad * 4;
                sH[row + 0][col] = (unsigned short)p01;
                sH[row + 1][col] = (unsigned short)(p01 >> 16);
                sH[row + 2][col] = (unsigned short)p23;
                sH[row + 3][col] = (unsigned short)(p23 >> 16);
            }
    }
    __syncthreads();

    // GEMM2: M=32, K=128, N=128
    {
        f32x4 acc[2][2];
#pragma unroll
        for (int mt = 0; mt < 2; mt++)
#pragma unroll
            for (int tl = 0; tl < 2; tl++) acc[mt][tl] = (f32x4){0.f, 0.f, 0.f, 0.f};
#pragma unroll
        for (int k0 = 0; k0 < 128; k0 += 32) {
            const short8 a0 = *(const short8*)&sH[c][k0 + quad * 8];
            const short8 a1 = *(const short8*)&sH[16 + c][k0 + quad * 8];
#pragma unroll
            for (int tl = 0; tl < 2; tl++) {
                const short8 b = *(const short8*)(Wt_n2 +
                    ((size_t)(n0 + tl * 16 + c) << 7) + k0 + quad * 8);
                acc[0][tl] = __builtin_amdgcn_mfma_f32_16x16x32_bf16(a0, b, acc[0][tl], 0, 0, 0);
                acc[1][tl] = __builtin_amdgcn_mfma_f32_16x16x32_bf16(a1, b, acc[1][tl], 0, 0, 0);
            }
        }
#pragma unroll
        for (int mt = 0; mt < 2; mt++)
#pragma unroll
            for (int tl = 0; tl < 2; tl++) {
                const int col = n0 + tl * 16 + c;
                const float bb = bn2[col];
#pragma unroll
                for (int r = 0; r < 4; r++) {
                    const int row = mt * 16 + quad * 4 + r;
                    out_h[(size_t)(node0 + row) * 128 + col] = acc[mt][tl][r] + bb;
                }
            }
    }
}

// ---------------------------------------------------------------------------
extern "C" void kernel_launch(void* const* d_in, const int* in_sizes, int n_in,
                              void* d_out, int out_size, void* d_ws, size_t ws_size,
                              hipStream_t stream) {
    const float* nf    = (const float*)d_in[0];
    const float* coord = (const float*)d_in[1];
    const int*   src   = (const int*)d_in[2];
    const int*   dst   = (const int*)d_in[3];
    const float* We1   = (const float*)d_in[4];
    const float* be1   = (const float*)d_in[5];
    const float* We2   = (const float*)d_in[6];
    const float* be2   = (const float*)d_in[7];
    const float* Wn1   = (const float*)d_in[8];
    const float* bn1   = (const float*)d_in[9];
    const float* Wn2   = (const float*)d_in[10];
    const float* bn2   = (const float*)d_in[11];
    const float* Wc1   = (const float*)d_in[12];
    const float* bc1   = (const float*)d_in[13];
    const float* Wc2   = (const float*)d_in[14];

    unsigned short* Pc = (unsigned short*)d_ws;            // N*256 bf16
    float* hn = (float*)(Pc + (size_t)N_NODES * 256);      // N*128 f32
    float* xs = hn + (size_t)N_NODES * 128;                // N*4
    int* deg       = (int*)(xs + (size_t)N_NODES * 4);     // N
    int* rsl       = deg + N_NODES;                        // N (block-local excl scan)
    int* cursor    = rsl + N_NODES;                        // N
    int* btot      = cursor + N_NODES;                     // 64
    int* elist     = btot + 64;                            // E
    unsigned short* Wt_e1 = (unsigned short*)
        (((uintptr_t)(elist + N_EDGES) + 255) & ~(uintptr_t)255);  // 256*128
    unsigned short* Wt_e2 = Wt_e1 + 256 * 128;                     // 128*128
    unsigned short* Wt_c1 = Wt_e2 + 128 * 128;                     // 128*128
    unsigned short* Wt_n1 = Wt_c1 + 128 * 128;                     // 128*256
    unsigned short* Wt_n2 = Wt_n1 + 128 * 256;                     // 128*128

    float* out_h = (float*)d_out;                          // N*128
    float* out_x = out_h + (size_t)N_NODES * 128;          // N*3

    k_pack2<<<256, 128, 0, stream>>>(We1, We2, Wc1, Wn1, Wn2,
                                     Wt_e1, Wt_e2, Wt_c1, Wt_n1, Wt_n2,
                                     deg, cursor, xs, hn);
    k_cntpre<<<N_NODES / 64, 256, 0, stream>>>(nf, Wt_e1, be1, Pc, dst, deg);
    k_scanA<<<40, 1024, 0, stream>>>(deg, rsl, btot);
    k_fill<<<(N_EDGES + 255) / 256, 256, 0, stream>>>(dst, rsl, btot, cursor, elist);
    k_edge9<<<N_EDGES / 64, 256, 0, stream>>>(Pc, coord, src, dst, elist,
                                              We1, Wt_e2, be2, Wt_c1, bc1,
                                              Wc2, hn, xs);
    k_node<<<N_NODES / 32, 256, 0, stream>>>(nf, coord, hn, xs, deg,
                                             Wt_n1, bn1, Wt_n2, bn2, out_h, out_x);
}